// Round 8
// baseline (133.577 us; speedup 1.0000x reference)
//
#include <hip/hip_runtime.h>
#include <math.h>

#define DEV static __device__ __forceinline__

typedef __attribute__((ext_vector_type(4))) float f32x4;
typedef __attribute__((ext_vector_type(2))) unsigned u32x2;
typedef __attribute__((ext_vector_type(8))) __bf16 bf16x8;
typedef __attribute__((ext_vector_type(8))) unsigned short u16x8;
typedef __attribute__((ext_vector_type(4))) unsigned short u16x4;

constexpr int TB = 2;     // batch
constexpr int TT = 2048;  // seq len
constexpr int DM = 1024;  // model dim
constexpr int NH = 16;    // heads
constexpr int DH = 64;    // head dim
constexpr int MR = TB * TT;  // 4096 rows
constexpr int SQKV = 3 * DM; // fused QKV row stride

DEV unsigned short f2bf(float f) {
  union { float f; unsigned u; } v; v.f = f;
  return (unsigned short)((v.u + 0x7FFFu + ((v.u >> 16) & 1u)) >> 16);
}

DEV unsigned cvtpk(float a, float b) {  // lo=bf16(a), hi=bf16(b)
  unsigned r;
  asm("v_cvt_pk_bf16_f32 %0, %1, %2" : "=v"(r) : "v"(a), "v"(b));
  return r;
}

DEV void gld16(const void* g, void* l) {
  __builtin_amdgcn_global_load_lds((const __attribute__((address_space(1))) void*)g,
                                   (__attribute__((address_space(3))) void*)l, 16, 0, 0);
}

DEV bf16x8 ldsb8(const unsigned short* p) { return *(const bf16x8*)p; }

// ---------- merged preprocessing: 4 weight transposes + x fp32->bf16 ----------
__global__ __launch_bounds__(256) void k_prep(const float* __restrict__ x,
                                              const float* __restrict__ w0,
                                              const float* __restrict__ w1,
                                              const float* __restrict__ w2,
                                              const float* __restrict__ w3,
                                              unsigned short* __restrict__ xb,
                                              unsigned short* __restrict__ wtdst) {
  __shared__ float tile[32][33];
  const int id = blockIdx.x, tid = threadIdx.x;
  if (id < 4096) {
    const int z = id >> 10, tl = id & 1023;
    const float* w = z == 0 ? w0 : z == 1 ? w1 : z == 2 ? w2 : w3;
    unsigned short* wt = wtdst + (size_t)z * DM * DM;
    const int n0 = (tl & 31) * 32, k0 = (tl >> 5) * 32;
    const int tx = tid & 31, ty = tid >> 5;  // 32 x 8
#pragma unroll
    for (int yy = 0; yy < 32; yy += 8)
      tile[ty + yy][tx] = w[(size_t)(k0 + ty + yy) * DM + n0 + tx];
    __syncthreads();
#pragma unroll
    for (int yy = 0; yy < 32; yy += 8)
      wt[(size_t)(n0 + ty + yy) * DM + k0 + tx] = f2bf(tile[tx][ty + yy]);
  } else {
    const int i = ((id - 4096) * 256 + tid) * 8;
    f32x4 a = *(const f32x4*)(x + i);
    f32x4 b = *(const f32x4*)(x + i + 4);
    u16x8 o;
#pragma unroll
    for (int j = 0; j < 4; ++j) { o[j] = f2bf(a[j]); o[j + 4] = f2bf(b[j]); }
    *(u16x8*)(xb + i) = o;
  }
}

// ---------- NT GEMM: C[M][N] = A[M][K] * Bt[N][K]^T, bf16 in, fp32 acc ----------
// Columns col < scol get scaled by ascale (pre-scale Q). If vt != nullptr,
// columns col >= 2*DM are written to the PV-native Vt layout:
// Vt[bh][t][d][chunk][8] with chunk = (ks*4+lg) ^ (d&7), entry e =
// {V[ks*32+lg*4+r][d] r=0..3, V[ks*32+16+lg*4+r][d] r=0..3}.
DEV void store_c(float* p, float v) { *p = v; }
DEV void store_c(unsigned short* p, float v) { *p = f2bf(v); }

template <typename OUT_T>
__global__ __launch_bounds__(256) void k_gemm_nt(const unsigned short* __restrict__ A,
                                                 const unsigned short* __restrict__ Bt,
                                                 OUT_T* __restrict__ C, int M, int N, int K,
                                                 float ascale, int scol,
                                                 unsigned short* __restrict__ vt) {
  __shared__ alignas(16) unsigned short As[128 * 32];
  __shared__ alignas(16) unsigned short Bs[128 * 32];
  const int tid = threadIdx.x;
  const int m0 = blockIdx.y * 128, n0 = blockIdx.x * 128;
  const int lane = tid & 63, w = tid >> 6;
  const int lr = lane & 15, lg = lane >> 4;
  const int wm = w >> 1, wn = w & 1;
  f32x4 acc[4][4] = {};
  for (int k0 = 0; k0 < K; k0 += 32) {
#pragma unroll
    for (int j = 0; j < 2; ++j) {
      int ci = j * 256 + tid;
      gld16(A + (size_t)(m0 + (ci >> 2)) * K + k0 + (ci & 3) * 8, (void*)(As + ci * 8));
      gld16(Bt + (size_t)(n0 + (ci >> 2)) * K + k0 + (ci & 3) * 8, (void*)(Bs + ci * 8));
    }
    __syncthreads();
    bf16x8 af[4], bfr[4];
#pragma unroll
    for (int i = 0; i < 4; ++i) af[i] = ldsb8(As + (wm * 64 + i * 16 + lr) * 32 + lg * 8);
#pragma unroll
    for (int j = 0; j < 4; ++j) bfr[j] = ldsb8(Bs + (wn * 64 + j * 16 + lr) * 32 + lg * 8);
#pragma unroll
    for (int i = 0; i < 4; ++i)
#pragma unroll
      for (int j = 0; j < 4; ++j)
        acc[i][j] = __builtin_amdgcn_mfma_f32_16x16x32_bf16(af[i], bfr[j], acc[i][j], 0, 0, 0);
    __syncthreads();
  }
#pragma unroll
  for (int i = 0; i < 4; ++i)
#pragma unroll
    for (int j = 0; j < 4; ++j) {
      const int row = m0 + wm * 64 + i * 16 + lg * 4;
      const int col = n0 + wn * 64 + j * 16 + lr;
      if (vt && col >= 2 * DM) {
        const int hh = (col - 2 * DM) >> 6, dd = (col - 2 * DM) & 63;
        const int bb = row >> 11, sg = row & (TT - 1);
        const int t = sg >> 6, sl = sg & 63;
        const int g = ((sl >> 5) << 2) | ((sl >> 2) & 3);  // ks*4 + lg-of-s
        const int half = (sl >> 4) & 1;
        const int cch = g ^ (dd & 7);
        u16x4 pk;
#pragma unroll
        for (int r = 0; r < 4; ++r) pk[r] = f2bf(acc[i][j][r]);
        *(u16x4*)(vt + (size_t)((bb * NH + hh) * 32 + t) * 4096 + dd * 64 + cch * 8 + half * 4) = pk;
      } else {
#pragma unroll
        for (int r = 0; r < 4; ++r) {
          float v = acc[i][j][r];
          if (col < scol) v *= ascale;
          store_c(C + (size_t)(row + r) * N + col, v);
        }
      }
    }
}

// ---------- causal flash attention v8 ----------
// 128-row q-tiles, 8 waves x 16 q-rows, 512 threads, grid 512 (2 blocks/CU;
// ids c and c+256 share a CU -> pair (pi, 15-pi): per-CU work uniform = 34).
// KV tiles of 64 double-buffered; K [s][d] XOR-swizzled (b128); V in PV-native
// layout (linear stage, conflict-free b128); P stays in registers (k-map).
__global__ __launch_bounds__(512, 4) void k_attn8(const unsigned short* __restrict__ QKV,
                                                  const unsigned short* __restrict__ Vt,
                                                  unsigned short* __restrict__ O) {
  __shared__ alignas(16) unsigned short Ks[2][64 * 64];
  __shared__ alignas(16) unsigned short Vs[2][64 * 64];
  const int id = blockIdx.x;
  const int pairIdx = id & 255;
  const int bh = pairIdx >> 3, pi = pairIdx & 7;
  const int j = (id < 256) ? pi : 15 - pi;
  const int b = bh >> 4, h = bh & 15;
  const int q0 = j * 128;
  const int tid = threadIdx.x, lane = tid & 63, w = tid >> 6;
  const int lr = lane & 15, lg = lane >> 4;
  const int lsw = lr & 7;  // XOR key (row&7 / d&7 for all our reads)
  const int qw = q0 + w * 16;
  const unsigned short* Qg = QKV + (size_t)b * TT * SQKV + h * DH;
  const unsigned short* Kg = QKV + (size_t)b * TT * SQKV + DM + h * DH;
  const unsigned short* Vg = Vt + (size_t)bh * 32 * 4096;  // PV-native tiles

  // Q fragment (B-operand role): lane holds Q[qw+lr][c*32 + lg*8 ..] (pre-scaled)
  bf16x8 qf[2];
#pragma unroll
  for (int c2 = 0; c2 < 2; ++c2)
    qf[c2] = *(const bf16x8*)(Qg + (size_t)(qw + lr) * SQKV + c2 * 32 + lg * 8);

  f32x4 acco[4] = {};
  float mrun = -1e30f, lrun = 0.f;

  // stage: K row-swizzled; V is a linear 8KB tile copy (layout pre-arranged)
  const int krow = tid >> 3, kcc = (tid & 7) ^ (krow & 7);
  const unsigned short* kbase = Kg + (size_t)krow * SQKV + kcc * 8;
  const unsigned short* vbase = Vg + tid * 8;
  auto stage = [&](int buf, int t) {
    gld16(kbase + (size_t)t * 64 * SQKV, (void*)(Ks[buf] + tid * 8));
    gld16(vbase + (size_t)t * 4096, (void*)(Vs[buf] + tid * 8));
  };

  const int nt = 2 * j + 2;
  stage(0, 0);
  for (int t = 0; t < nt; ++t) {
    const int buf = t & 1;
    if (t + 1 < nt) {
      stage(buf ^ 1, t + 1);
      asm volatile("s_waitcnt vmcnt(2)" ::: "memory");  // tile t landed; t+1 in flight
    } else {
      asm volatile("s_waitcnt vmcnt(0)" ::: "memory");
    }
    __builtin_amdgcn_s_barrier();
    const int s0 = t * 64;
    if (s0 <= qw + 15) {  // not fully masked for this wave
      const unsigned short* Kb_ = Ks[buf];
      const unsigned short* Vb_ = Vs[buf];
      // ---- S^T = K Q^T : st[ct] holds S[s=s0+ct*16+lg*4+r][q=qw+lr] (exp2 dom) ----
      f32x4 st[4] = {};
      __builtin_amdgcn_s_setprio(1);
#pragma unroll
      for (int ct = 0; ct < 4; ++ct)
#pragma unroll
        for (int c2 = 0; c2 < 2; ++c2) {
          bf16x8 kf = ldsb8(Kb_ + (ct * 16 + lr) * 64 + (((c2 * 4 + lg) ^ lsw) * 8));
          st[ct] = __builtin_amdgcn_mfma_f32_16x16x32_bf16(kf, qf[c2], st[ct], 0, 0, 0);
        }
      __builtin_amdgcn_s_setprio(0);
      // ---- lane-local softmax over 16 s-values (+2 shuffles across lg) ----
      float p[4][4];
      const bool diag = (s0 + 63 >= qw);
      const int qrel = qw + lr - s0;
      if (diag) {
#pragma unroll
        for (int ct = 0; ct < 4; ++ct)
#pragma unroll
          for (int r = 0; r < 4; ++r) {
            float v = st[ct][r];
            if (ct * 16 + lg * 4 + r > qrel) v = -1e30f;
            p[ct][r] = v;
          }
      } else {
#pragma unroll
        for (int ct = 0; ct < 4; ++ct)
#pragma unroll
          for (int r = 0; r < 4; ++r) p[ct][r] = st[ct][r];
      }
      float m0_ = fmaxf(fmaxf(p[0][0], p[0][1]), p[0][2]);
      float m1_ = fmaxf(fmaxf(p[0][3], p[1][0]), p[1][1]);
      float m2_ = fmaxf(fmaxf(p[1][2], p[1][3]), p[2][0]);
      float m3_ = fmaxf(fmaxf(p[2][1], p[2][2]), p[2][3]);
      float m4_ = fmaxf(fmaxf(p[3][0], p[3][1]), p[3][2]);
      float mx = fmaxf(fmaxf(fmaxf(m0_, m1_), fmaxf(m2_, m3_)), fmaxf(m4_, p[3][3]));
      mx = fmaxf(mx, __shfl_xor(mx, 16));
      mx = fmaxf(mx, __shfl_xor(mx, 32));
      // defer-max: only rescale when the running max grew by > 11.5 (e^8 analog)
      if (!__all(mx <= mrun + 11.5f)) {
        const float mn = fmaxf(mrun, mx);
        const float aa = __builtin_exp2f(mrun - mn);
        mrun = mn;
        lrun *= aa;
        float aab[4];
#pragma unroll
        for (int r = 0; r < 4; ++r) aab[r] = __shfl(aa, lg * 4 + r);
#pragma unroll
        for (int dt = 0; dt < 4; ++dt)
#pragma unroll
          for (int r = 0; r < 4; ++r) acco[dt][r] *= aab[r];
      }
      f32x4 rs4 = {0.f, 0.f, 0.f, 0.f};
#pragma unroll
      for (int ct = 0; ct < 4; ++ct)
#pragma unroll
        for (int r = 0; r < 4; ++r) {
          p[ct][r] = __builtin_exp2f(p[ct][r] - mrun);
          rs4[r] += p[ct][r];
        }
      float rs = (rs4[0] + rs4[1]) + (rs4[2] + rs4[3]);
      rs += __shfl_xor(rs, 16);
      rs += __shfl_xor(rs, 32);
      lrun += rs;
      // ---- P in registers: pf[ks] = lane-local A-fragment (custom k-map) ----
      bf16x8 pf[2];
#pragma unroll
      for (int ks = 0; ks < 2; ++ks) {
        union { unsigned w4[4]; bf16x8 v; } pu;
        pu.w4[0] = cvtpk(p[2 * ks][0], p[2 * ks][1]);
        pu.w4[1] = cvtpk(p[2 * ks][2], p[2 * ks][3]);
        pu.w4[2] = cvtpk(p[2 * ks + 1][0], p[2 * ks + 1][1]);
        pu.w4[3] = cvtpk(p[2 * ks + 1][2], p[2 * ks + 1][3]);
        pf[ks] = pu.v;
      }
      // ---- O += P V^T : V B-frag = single b128 from PV-native layout ----
      __builtin_amdgcn_s_setprio(1);
#pragma unroll
      for (int dt = 0; dt < 4; ++dt) {
        const unsigned short* Vrow = Vb_ + (dt * 16 + lr) * 64;  // d&7 == lsw
#pragma unroll
        for (int ks = 0; ks < 2; ++ks) {
          bf16x8 vf = ldsb8(Vrow + (((ks * 4 + lg) ^ lsw) * 8));
          acco[dt] = __builtin_amdgcn_mfma_f32_16x16x32_bf16(pf[ks], vf, acco[dt], 0, 0, 0);
        }
      }
      __builtin_amdgcn_s_setprio(0);
    }
    __builtin_amdgcn_s_barrier();  // protect buf before next stage overwrites it
  }
  // ---- epilogue ----
  const float linv = 1.f / lrun;
  float lb[4];
#pragma unroll
  for (int r = 0; r < 4; ++r) lb[r] = __shfl(linv, lg * 4 + r);
#pragma unroll
  for (int dt = 0; dt < 4; ++dt)
#pragma unroll
    for (int r = 0; r < 4; ++r) {
      const int q = qw + lg * 4 + r;
      O[(size_t)(b * TT + q) * DM + h * DH + dt * 16 + lr] = f2bf(acco[dt][r] * lb[r]);
    }
}

extern "C" void kernel_launch(void* const* d_in, const int* in_sizes, int n_in,
                              void* d_out, int out_size, void* d_ws, size_t ws_size,
                              hipStream_t stream) {
  const float* x = (const float*)d_in[0];
  const float* wq = (const float*)d_in[1];
  const float* wk = (const float*)d_in[2];
  const float* wv = (const float*)d_in[3];
  const float* wo = (const float*)d_in[4];
  float* out = (float*)d_out;
  char* ws = (char*)d_ws;
  const size_t MB = 1u << 20;
  // ws layout (48 MB):
  unsigned short* xb = (unsigned short*)(ws);             // 8MB: x bf16; reused as attn-out
  unsigned short* wqt = (unsigned short*)(ws + 8 * MB);   // 2MB x4 contiguous: wq^T wk^T wv^T wo^T
  unsigned short* wot = (unsigned short*)(ws + 14 * MB);
  unsigned short* QKVb = (unsigned short*)(ws + 16 * MB); // 24MB: [MR][3072] (V region unused)
  unsigned short* Vtb = (unsigned short*)(ws + 40 * MB);  // 8MB: PV-native [B*H][32][4096]

  k_prep<<<dim3(6144), 256, 0, stream>>>(x, wq, wk, wv, wo, xb, wqt);
  // Q columns (col < DM) pre-scaled by 0.125*log2(e); V columns -> PV-native Vtb
  k_gemm_nt<unsigned short><<<dim3(24, 32), 256, 0, stream>>>(xb, wqt, QKVb, MR, SQKV, DM,
                                                              0.18033688f, DM, Vtb);
  k_attn8<<<dim3(512), 512, 0, stream>>>(QKVb, Vtb, xb);
  k_gemm_nt<float><<<dim3(8, 32), 256, 0, stream>>>(xb, wot, out, MR, DM, DM, 1.0f, 0, nullptr);
}

// Round 9
// 132.412 us; speedup vs baseline: 1.0088x; 1.0088x over previous
//
#include <hip/hip_runtime.h>
#include <math.h>

#define DEV static __device__ __forceinline__

typedef __attribute__((ext_vector_type(4))) float f32x4;
typedef __attribute__((ext_vector_type(2))) unsigned u32x2;
typedef __attribute__((ext_vector_type(8))) __bf16 bf16x8;
typedef __attribute__((ext_vector_type(8))) unsigned short u16x8;
typedef __attribute__((ext_vector_type(4))) unsigned short u16x4;

constexpr int TB = 2;     // batch
constexpr int TT = 2048;  // seq len
constexpr int DM = 1024;  // model dim
constexpr int NH = 16;    // heads
constexpr int DH = 64;    // head dim
constexpr int MR = TB * TT;  // 4096 rows
constexpr int SQKV = 3 * DM; // fused QKV row stride

DEV unsigned short f2bf(float f) {
  union { float f; unsigned u; } v; v.f = f;
  return (unsigned short)((v.u + 0x7FFFu + ((v.u >> 16) & 1u)) >> 16);
}

DEV unsigned cvtpk(float a, float b) {  // lo=bf16(a), hi=bf16(b)
  unsigned r;
  asm("v_cvt_pk_bf16_f32 %0, %1, %2" : "=v"(r) : "v"(a), "v"(b));
  return r;
}

DEV void gld16(const void* g, void* l) {
  __builtin_amdgcn_global_load_lds((const __attribute__((address_space(1))) void*)g,
                                   (__attribute__((address_space(3))) void*)l, 16, 0, 0);
}

DEV bf16x8 ldsb8(const unsigned short* p) { return *(const bf16x8*)p; }

// ---------- merged preprocessing: 4 weight transposes + x fp32->bf16 ----------
__global__ __launch_bounds__(256) void k_prep(const float* __restrict__ x,
                                              const float* __restrict__ w0,
                                              const float* __restrict__ w1,
                                              const float* __restrict__ w2,
                                              const float* __restrict__ w3,
                                              unsigned short* __restrict__ xb,
                                              unsigned short* __restrict__ wtdst) {
  __shared__ float tile[32][33];
  const int id = blockIdx.x, tid = threadIdx.x;
  if (id < 4096) {
    const int z = id >> 10, tl = id & 1023;
    const float* w = z == 0 ? w0 : z == 1 ? w1 : z == 2 ? w2 : w3;
    unsigned short* wt = wtdst + (size_t)z * DM * DM;
    const int n0 = (tl & 31) * 32, k0 = (tl >> 5) * 32;
    const int tx = tid & 31, ty = tid >> 5;  // 32 x 8
#pragma unroll
    for (int yy = 0; yy < 32; yy += 8)
      tile[ty + yy][tx] = w[(size_t)(k0 + ty + yy) * DM + n0 + tx];
    __syncthreads();
#pragma unroll
    for (int yy = 0; yy < 32; yy += 8)
      wt[(size_t)(n0 + ty + yy) * DM + k0 + tx] = f2bf(tile[tx][ty + yy]);
  } else {
    const int i = ((id - 4096) * 256 + tid) * 8;
    f32x4 a = *(const f32x4*)(x + i);
    f32x4 b = *(const f32x4*)(x + i + 4);
    u16x8 o;
#pragma unroll
    for (int j = 0; j < 4; ++j) { o[j] = f2bf(a[j]); o[j + 4] = f2bf(b[j]); }
    *(u16x8*)(xb + i) = o;
  }
}

// ---------- QKV GEMM: C[M][3072] = A[M][K] * Bt[3072][K]^T ----------
// Q columns (col<DM) pre-scaled by ascale; V columns (col>=2*DM) written to
// PV-native Vt layout: Vt[bh][t][d][chunk][8], chunk = (ks*4+lg) ^ (d&7).
DEV void store_c(float* p, float v) { *p = v; }
DEV void store_c(unsigned short* p, float v) { *p = f2bf(v); }

__global__ __launch_bounds__(256) void k_gemm_qkv(const unsigned short* __restrict__ A,
                                                  const unsigned short* __restrict__ Bt,
                                                  unsigned short* __restrict__ C,
                                                  float ascale,
                                                  unsigned short* __restrict__ vt) {
  constexpr int K = DM, N = SQKV;
  __shared__ alignas(16) unsigned short As[128 * 32];
  __shared__ alignas(16) unsigned short Bs[128 * 32];
  const int tid = threadIdx.x;
  const int m0 = blockIdx.y * 128, n0 = blockIdx.x * 128;
  const int lane = tid & 63, w = tid >> 6;
  const int lr = lane & 15, lg = lane >> 4;
  const int wm = w >> 1, wn = w & 1;
  f32x4 acc[4][4] = {};
  for (int k0 = 0; k0 < K; k0 += 32) {
#pragma unroll
    for (int j = 0; j < 2; ++j) {
      int ci = j * 256 + tid;
      gld16(A + (size_t)(m0 + (ci >> 2)) * K + k0 + (ci & 3) * 8, (void*)(As + ci * 8));
      gld16(Bt + (size_t)(n0 + (ci >> 2)) * K + k0 + (ci & 3) * 8, (void*)(Bs + ci * 8));
    }
    __syncthreads();
    bf16x8 af[4], bfr[4];
#pragma unroll
    for (int i = 0; i < 4; ++i) af[i] = ldsb8(As + (wm * 64 + i * 16 + lr) * 32 + lg * 8);
#pragma unroll
    for (int j = 0; j < 4; ++j) bfr[j] = ldsb8(Bs + (wn * 64 + j * 16 + lr) * 32 + lg * 8);
#pragma unroll
    for (int i = 0; i < 4; ++i)
#pragma unroll
      for (int j = 0; j < 4; ++j)
        acc[i][j] = __builtin_amdgcn_mfma_f32_16x16x32_bf16(af[i], bfr[j], acc[i][j], 0, 0, 0);
    __syncthreads();
  }
#pragma unroll
  for (int i = 0; i < 4; ++i)
#pragma unroll
    for (int j = 0; j < 4; ++j) {
      const int row = m0 + wm * 64 + i * 16 + lg * 4;
      const int col = n0 + wn * 64 + j * 16 + lr;
      if (col >= 2 * DM) {
        const int hh = (col - 2 * DM) >> 6, dd = (col - 2 * DM) & 63;
        const int bb = row >> 11, sg = row & (TT - 1);
        const int t = sg >> 6, sl = sg & 63;
        const int g = ((sl >> 5) << 2) | ((sl >> 2) & 3);  // ks*4 + lg-of-s
        const int half = (sl >> 4) & 1;
        const int cch = g ^ (dd & 7);
        u16x4 pk;
#pragma unroll
        for (int r = 0; r < 4; ++r) pk[r] = f2bf(acc[i][j][r]);
        *(u16x4*)(vt + (size_t)((bb * NH + hh) * 32 + t) * 4096 + dd * 64 + cch * 8 + half * 4) = pk;
      } else {
        const float s = (col < DM) ? ascale : 1.0f;
#pragma unroll
        for (int r = 0; r < 4; ++r)
          store_c(C + (size_t)(row + r) * N + col, acc[i][j][r] * s);
      }
    }
}

// ---------- out-proj GEMM: C[M][1024] fp32 = A[M][K]bf16 * Bt[1024][K]^T ----------
// 128x64 tiles, grid (16,32) = 512 blocks (2/CU); wave w: 64x32 sub-tile.
__global__ __launch_bounds__(256) void k_gemm_out(const unsigned short* __restrict__ A,
                                                  const unsigned short* __restrict__ Bt,
                                                  float* __restrict__ C) {
  constexpr int K = DM, N = DM;
  __shared__ alignas(16) unsigned short As[128 * 32];
  __shared__ alignas(16) unsigned short Bs[64 * 32];
  const int tid = threadIdx.x;
  const int m0 = blockIdx.y * 128, n0 = blockIdx.x * 64;
  const int lane = tid & 63, w = tid >> 6;
  const int lr = lane & 15, lg = lane >> 4;
  const int wm = w >> 1, wn = w & 1;
  f32x4 acc[4][2] = {};
  for (int k0 = 0; k0 < K; k0 += 32) {
#pragma unroll
    for (int j = 0; j < 2; ++j) {
      int ci = j * 256 + tid;
      gld16(A + (size_t)(m0 + (ci >> 2)) * K + k0 + (ci & 3) * 8, (void*)(As + ci * 8));
    }
    {
      int ci = tid;  // 256 chunks for B 64x32
      gld16(Bt + (size_t)(n0 + (ci >> 2)) * K + k0 + (ci & 3) * 8, (void*)(Bs + ci * 8));
    }
    __syncthreads();
    bf16x8 af[4], bfr[2];
#pragma unroll
    for (int i = 0; i < 4; ++i) af[i] = ldsb8(As + (wm * 64 + i * 16 + lr) * 32 + lg * 8);
#pragma unroll
    for (int j = 0; j < 2; ++j) bfr[j] = ldsb8(Bs + (wn * 32 + j * 16 + lr) * 32 + lg * 8);
#pragma unroll
    for (int i = 0; i < 4; ++i)
#pragma unroll
      for (int j = 0; j < 2; ++j)
        acc[i][j] = __builtin_amdgcn_mfma_f32_16x16x32_bf16(af[i], bfr[j], acc[i][j], 0, 0, 0);
    __syncthreads();
  }
#pragma unroll
  for (int i = 0; i < 4; ++i)
#pragma unroll
    for (int j = 0; j < 2; ++j) {
      const int row = m0 + wm * 64 + i * 16 + lg * 4;
      const int col = n0 + wn * 32 + j * 16 + lr;
#pragma unroll
      for (int r = 0; r < 4; ++r) C[(size_t)(row + r) * N + col] = acc[i][j][r];
    }
}

// ---------- causal flash attention v9 ----------
// R8 structure (128-row q-tiles, 8 waves, grid 512 balanced pairs, PV-native V,
// in-register P) + triple-buffered LDS with a SINGLE barrier per KV tile:
// per iter: vmcnt(2) -> s_barrier -> issue stage(t+2) -> compute(t).
__global__ __launch_bounds__(512) void k_attn9(const unsigned short* __restrict__ QKV,
                                               const unsigned short* __restrict__ Vt,
                                               unsigned short* __restrict__ O) {
  __shared__ alignas(16) unsigned short Ks[3][64 * 64];
  __shared__ alignas(16) unsigned short Vs[3][64 * 64];
  const int id = blockIdx.x;
  const int pairIdx = id & 255;
  const int bh = pairIdx >> 3, pi = pairIdx & 7;
  const int j = (id < 256) ? pi : 15 - pi;
  const int b = bh >> 4, h = bh & 15;
  const int q0 = j * 128;
  const int tid = threadIdx.x, lane = tid & 63, w = tid >> 6;
  const int lr = lane & 15, lg = lane >> 4;
  const int lsw = lr & 7;  // XOR key (row&7 / d&7 for all our reads)
  const int qw = q0 + w * 16;
  const unsigned short* Qg = QKV + (size_t)b * TT * SQKV + h * DH;
  const unsigned short* Kg = QKV + (size_t)b * TT * SQKV + DM + h * DH;
  const unsigned short* Vg = Vt + (size_t)bh * 32 * 4096;  // PV-native tiles

  // Q fragment (B-operand role): lane holds Q[qw+lr][c*32 + lg*8 ..] (pre-scaled)
  bf16x8 qf[2];
#pragma unroll
  for (int c2 = 0; c2 < 2; ++c2)
    qf[c2] = *(const bf16x8*)(Qg + (size_t)(qw + lr) * SQKV + c2 * 32 + lg * 8);

  f32x4 acco[4] = {};
  float mrun = -1e30f, lrun = 0.f;

  // stage: K row-swizzled; V is a linear 8KB tile copy (layout pre-arranged)
  const int krow = tid >> 3, kcc = (tid & 7) ^ (krow & 7);
  const unsigned short* kbase = Kg + (size_t)krow * SQKV + kcc * 8;
  const unsigned short* vbase = Vg + tid * 8;
  auto stage = [&](int buf, int t) {
    gld16(kbase + (size_t)t * 64 * SQKV, (void*)(Ks[buf] + tid * 8));
    gld16(vbase + (size_t)t * 4096, (void*)(Vs[buf] + tid * 8));
  };

  const int nt = 2 * j + 2;
  stage(0, 0);
  stage(1, 1);  // nt >= 2 always
  int buf = 0;
  for (int t = 0; t < nt; ++t) {
    if (t + 1 < nt) {
      asm volatile("s_waitcnt vmcnt(2)" ::: "memory");  // tile t landed; t+1 in flight
    } else {
      asm volatile("s_waitcnt vmcnt(0)" ::: "memory");
    }
    __builtin_amdgcn_s_barrier();
    if (t + 2 < nt) {
      int nb = buf + 2; if (nb >= 3) nb -= 3;
      stage(nb, t + 2);  // targets buf[(t+2)%3] = buf[(t-1)%3]; all waves done with it
    }
    const int s0 = t * 64;
    if (s0 <= qw + 15) {  // not fully masked for this wave
      const unsigned short* Kb_ = Ks[buf];
      const unsigned short* Vb_ = Vs[buf];
      // ---- S^T = K Q^T : st[ct] holds S[s=s0+ct*16+lg*4+r][q=qw+lr] (exp2 dom) ----
      f32x4 st[4] = {};
      __builtin_amdgcn_s_setprio(1);
#pragma unroll
      for (int ct = 0; ct < 4; ++ct)
#pragma unroll
        for (int c2 = 0; c2 < 2; ++c2) {
          bf16x8 kf = ldsb8(Kb_ + (ct * 16 + lr) * 64 + (((c2 * 4 + lg) ^ lsw) * 8));
          st[ct] = __builtin_amdgcn_mfma_f32_16x16x32_bf16(kf, qf[c2], st[ct], 0, 0, 0);
        }
      __builtin_amdgcn_s_setprio(0);
      // ---- lane-local softmax over 16 s-values (+2 shuffles across lg) ----
      float p[4][4];
      const bool diag = (s0 + 63 >= qw);
      const int qrel = qw + lr - s0;
      if (diag) {
#pragma unroll
        for (int ct = 0; ct < 4; ++ct)
#pragma unroll
          for (int r = 0; r < 4; ++r) {
            float v = st[ct][r];
            if (ct * 16 + lg * 4 + r > qrel) v = -1e30f;
            p[ct][r] = v;
          }
      } else {
#pragma unroll
        for (int ct = 0; ct < 4; ++ct)
#pragma unroll
          for (int r = 0; r < 4; ++r) p[ct][r] = st[ct][r];
      }
      float m0_ = fmaxf(fmaxf(p[0][0], p[0][1]), p[0][2]);
      float m1_ = fmaxf(fmaxf(p[0][3], p[1][0]), p[1][1]);
      float m2_ = fmaxf(fmaxf(p[1][2], p[1][3]), p[2][0]);
      float m3_ = fmaxf(fmaxf(p[2][1], p[2][2]), p[2][3]);
      float m4_ = fmaxf(fmaxf(p[3][0], p[3][1]), p[3][2]);
      float mx = fmaxf(fmaxf(fmaxf(m0_, m1_), fmaxf(m2_, m3_)), fmaxf(m4_, p[3][3]));
      mx = fmaxf(mx, __shfl_xor(mx, 16));
      mx = fmaxf(mx, __shfl_xor(mx, 32));
      // defer-max: only rescale when the running max grew by > 11.5 (e^8 analog)
      if (!__all(mx <= mrun + 11.5f)) {
        const float mn = fmaxf(mrun, mx);
        const float aa = __builtin_exp2f(mrun - mn);
        mrun = mn;
        lrun *= aa;
        float aab[4];
#pragma unroll
        for (int r = 0; r < 4; ++r) aab[r] = __shfl(aa, lg * 4 + r);
#pragma unroll
        for (int dt = 0; dt < 4; ++dt)
#pragma unroll
          for (int r = 0; r < 4; ++r) acco[dt][r] *= aab[r];
      }
      f32x4 rs4 = {0.f, 0.f, 0.f, 0.f};
#pragma unroll
      for (int ct = 0; ct < 4; ++ct)
#pragma unroll
        for (int r = 0; r < 4; ++r) {
          p[ct][r] = __builtin_exp2f(p[ct][r] - mrun);
          rs4[r] += p[ct][r];
        }
      float rs = (rs4[0] + rs4[1]) + (rs4[2] + rs4[3]);
      rs += __shfl_xor(rs, 16);
      rs += __shfl_xor(rs, 32);
      lrun += rs;
      // ---- P in registers: pf[ks] = lane-local A-fragment (custom k-map) ----
      bf16x8 pf[2];
#pragma unroll
      for (int ks = 0; ks < 2; ++ks) {
        union { unsigned w4[4]; bf16x8 v; } pu;
        pu.w4[0] = cvtpk(p[2 * ks][0], p[2 * ks][1]);
        pu.w4[1] = cvtpk(p[2 * ks][2], p[2 * ks][3]);
        pu.w4[2] = cvtpk(p[2 * ks + 1][0], p[2 * ks + 1][1]);
        pu.w4[3] = cvtpk(p[2 * ks + 1][2], p[2 * ks + 1][3]);
        pf[ks] = pu.v;
      }
      // ---- O += P V^T : V B-frag = single b128 from PV-native layout ----
      __builtin_amdgcn_s_setprio(1);
#pragma unroll
      for (int dt = 0; dt < 4; ++dt) {
        const unsigned short* Vrow = Vb_ + (dt * 16 + lr) * 64;  // d&7 == lsw
#pragma unroll
        for (int ks = 0; ks < 2; ++ks) {
          bf16x8 vf = ldsb8(Vrow + (((ks * 4 + lg) ^ lsw) * 8));
          acco[dt] = __builtin_amdgcn_mfma_f32_16x16x32_bf16(pf[ks], vf, acco[dt], 0, 0, 0);
        }
      }
      __builtin_amdgcn_s_setprio(0);
    }
    if (++buf >= 3) buf = 0;
  }
  // ---- epilogue ----
  const float linv = 1.f / lrun;
  float lb[4];
#pragma unroll
  for (int r = 0; r < 4; ++r) lb[r] = __shfl(linv, lg * 4 + r);
#pragma unroll
  for (int dt = 0; dt < 4; ++dt)
#pragma unroll
    for (int r = 0; r < 4; ++r) {
      const int q = qw + lg * 4 + r;
      O[(size_t)(b * TT + q) * DM + h * DH + dt * 16 + lr] = f2bf(acco[dt][r] * lb[r]);
    }
}

extern "C" void kernel_launch(void* const* d_in, const int* in_sizes, int n_in,
                              void* d_out, int out_size, void* d_ws, size_t ws_size,
                              hipStream_t stream) {
  const float* x = (const float*)d_in[0];
  const float* wq = (const float*)d_in[1];
  const float* wk = (const float*)d_in[2];
  const float* wv = (const float*)d_in[3];
  const float* wo = (const float*)d_in[4];
  float* out = (float*)d_out;
  char* ws = (char*)d_ws;
  const size_t MB = 1u << 20;
  // ws layout (48 MB):
  unsigned short* xb = (unsigned short*)(ws);             // 8MB: x bf16; reused as attn-out
  unsigned short* wqt = (unsigned short*)(ws + 8 * MB);   // 2MB x4 contiguous: wq^T wk^T wv^T wo^T
  unsigned short* wot = (unsigned short*)(ws + 14 * MB);
  unsigned short* QKVb = (unsigned short*)(ws + 16 * MB); // 24MB: [MR][3072] (V region unused)
  unsigned short* Vtb = (unsigned short*)(ws + 40 * MB);  // 8MB: PV-native [B*H][32][4096]

  k_prep<<<dim3(6144), 256, 0, stream>>>(x, wq, wk, wv, wo, xb, wqt);
  // Q columns (col < DM) pre-scaled by 0.125*log2(e); V columns -> PV-native Vtb
  k_gemm_qkv<<<dim3(24, 32), 256, 0, stream>>>(xb, wqt, QKVb, 0.18033688f, Vtb);
  k_attn9<<<dim3(512), 512, 0, stream>>>(QKVb, Vtb, xb);
  k_gemm_out<<<dim3(16, 32), 256, 0, stream>>>(xb, wot, out);
}

// Round 10
// 119.281 us; speedup vs baseline: 1.1198x; 1.1101x over previous
//
#include <hip/hip_runtime.h>
#include <math.h>

#define DEV static __device__ __forceinline__

typedef __attribute__((ext_vector_type(4))) float f32x4;
typedef __attribute__((ext_vector_type(2))) unsigned u32x2;
typedef __attribute__((ext_vector_type(8))) __bf16 bf16x8;
typedef __attribute__((ext_vector_type(8))) unsigned short u16x8;
typedef __attribute__((ext_vector_type(4))) unsigned short u16x4;

constexpr int TB = 2;     // batch
constexpr int TT = 2048;  // seq len
constexpr int DM = 1024;  // model dim
constexpr int NH = 16;    // heads
constexpr int DH = 64;    // head dim
constexpr int MR = TB * TT;  // 4096 rows
constexpr int SQKV = 3 * DM; // fused QKV row stride

DEV unsigned short f2bf(float f) {
  union { float f; unsigned u; } v; v.f = f;
  return (unsigned short)((v.u + 0x7FFFu + ((v.u >> 16) & 1u)) >> 16);
}

DEV unsigned cvtpk(float a, float b) {  // lo=bf16(a), hi=bf16(b)
  unsigned r;
  asm("v_cvt_pk_bf16_f32 %0, %1, %2" : "=v"(r) : "v"(a), "v"(b));
  return r;
}

DEV void gld16(const void* g, void* l) {
  __builtin_amdgcn_global_load_lds((const __attribute__((address_space(1))) void*)g,
                                   (__attribute__((address_space(3))) void*)l, 16, 0, 0);
}

DEV bf16x8 ldsb8(const unsigned short* p) { return *(const bf16x8*)p; }

// ---------- merged preprocessing: 4 weight transposes + x fp32->bf16 ----------
__global__ __launch_bounds__(256) void k_prep(const float* __restrict__ x,
                                              const float* __restrict__ w0,
                                              const float* __restrict__ w1,
                                              const float* __restrict__ w2,
                                              const float* __restrict__ w3,
                                              unsigned short* __restrict__ xb,
                                              unsigned short* __restrict__ wtdst) {
  __shared__ float tile[32][33];
  const int id = blockIdx.x, tid = threadIdx.x;
  if (id < 4096) {
    const int z = id >> 10, tl = id & 1023;
    const float* w = z == 0 ? w0 : z == 1 ? w1 : z == 2 ? w2 : w3;
    unsigned short* wt = wtdst + (size_t)z * DM * DM;
    const int n0 = (tl & 31) * 32, k0 = (tl >> 5) * 32;
    const int tx = tid & 31, ty = tid >> 5;  // 32 x 8
#pragma unroll
    for (int yy = 0; yy < 32; yy += 8)
      tile[ty + yy][tx] = w[(size_t)(k0 + ty + yy) * DM + n0 + tx];
    __syncthreads();
#pragma unroll
    for (int yy = 0; yy < 32; yy += 8)
      wt[(size_t)(n0 + ty + yy) * DM + k0 + tx] = f2bf(tile[tx][ty + yy]);
  } else {
    const int i = ((id - 4096) * 256 + tid) * 8;
    f32x4 a = *(const f32x4*)(x + i);
    f32x4 b = *(const f32x4*)(x + i + 4);
    u16x8 o;
#pragma unroll
    for (int j = 0; j < 4; ++j) { o[j] = f2bf(a[j]); o[j + 4] = f2bf(b[j]); }
    *(u16x8*)(xb + i) = o;
  }
}

DEV void store_c(float* p, float v) { *p = v; }
DEV void store_c(unsigned short* p, float v) { *p = f2bf(v); }

// ---------- QKV GEMM v2: 8 waves / 128x128 tile, chunk-XOR swizzled LDS ----------
// Q columns (col<DM) pre-scaled by ascale; V columns (col>=2*DM) written to
// PV-native Vt layout: Vt[bh][t][d][chunk][8], chunk = (ks*4+lg) ^ (d&7).
__global__ __launch_bounds__(512) void k_gemm_qkv(const unsigned short* __restrict__ A,
                                                  const unsigned short* __restrict__ Bt,
                                                  unsigned short* __restrict__ C,
                                                  float ascale,
                                                  unsigned short* __restrict__ vt) {
  constexpr int K = DM, N = SQKV;
  __shared__ alignas(16) unsigned short As[128 * 32];
  __shared__ alignas(16) unsigned short Bs[128 * 32];
  const int tid = threadIdx.x;
  const int m0 = blockIdx.y * 128, n0 = blockIdx.x * 128;
  const int lane = tid & 63, w = tid >> 6;
  const int lr = lane & 15, lg = lane >> 4;
  const int wm = w >> 2, wn = w & 3;  // 2 x 4 waves; per-wave region 64 x 32
  // staging: 1 A-chunk + 1 B-chunk per thread; source chunk pre-swizzled
  const int srow = tid >> 2, scc = (tid & 3) ^ ((srow >> 1) & 3);
  const unsigned short* Ab = A + (size_t)(m0 + srow) * K + scc * 8;
  const unsigned short* Bb = Bt + (size_t)(n0 + srow) * K + scc * 8;
  f32x4 acc[4][2] = {};
  for (int k0 = 0; k0 < K; k0 += 32) {
    gld16(Ab + k0, (void*)(As + tid * 8));
    gld16(Bb + k0, (void*)(Bs + tid * 8));
    __syncthreads();
    bf16x8 af[4], bfr[2];
#pragma unroll
    for (int i = 0; i < 4; ++i) {
      const int row = wm * 64 + i * 16 + lr;
      af[i] = ldsb8(As + row * 32 + ((lg ^ ((row >> 1) & 3)) * 8));
    }
#pragma unroll
    for (int j = 0; j < 2; ++j) {
      const int row = wn * 32 + j * 16 + lr;
      bfr[j] = ldsb8(Bs + row * 32 + ((lg ^ ((row >> 1) & 3)) * 8));
    }
#pragma unroll
    for (int i = 0; i < 4; ++i)
#pragma unroll
      for (int j = 0; j < 2; ++j)
        acc[i][j] = __builtin_amdgcn_mfma_f32_16x16x32_bf16(af[i], bfr[j], acc[i][j], 0, 0, 0);
    __syncthreads();
  }
#pragma unroll
  for (int i = 0; i < 4; ++i)
#pragma unroll
    for (int j = 0; j < 2; ++j) {
      const int row = m0 + wm * 64 + i * 16 + lg * 4;
      const int col = n0 + wn * 32 + j * 16 + lr;
      if (col >= 2 * DM) {
        const int hh = (col - 2 * DM) >> 6, dd = (col - 2 * DM) & 63;
        const int bb = row >> 11, sg = row & (TT - 1);
        const int t = sg >> 6, sl = sg & 63;
        const int g = ((sl >> 5) << 2) | ((sl >> 2) & 3);  // ks*4 + lg-of-s
        const int half = (sl >> 4) & 1;
        const int cch = g ^ (dd & 7);
        u16x4 pk;
#pragma unroll
        for (int r = 0; r < 4; ++r) pk[r] = f2bf(acc[i][j][r]);
        *(u16x4*)(vt + (size_t)((bb * NH + hh) * 32 + t) * 4096 + dd * 64 + cch * 8 + half * 4) = pk;
      } else {
        const float s = (col < DM) ? ascale : 1.0f;
#pragma unroll
        for (int r = 0; r < 4; ++r)
          store_c(C + (size_t)(row + r) * N + col, acc[i][j][r] * s);
      }
    }
}

// ---------- out-proj GEMM v2: 8 waves / 128x64 tile, swizzled LDS ----------
__global__ __launch_bounds__(512) void k_gemm_out(const unsigned short* __restrict__ A,
                                                  const unsigned short* __restrict__ Bt,
                                                  float* __restrict__ C) {
  constexpr int K = DM, N = DM;
  __shared__ alignas(16) unsigned short As[128 * 32];
  __shared__ alignas(16) unsigned short Bs[64 * 32];
  const int tid = threadIdx.x;
  const int m0 = blockIdx.y * 128, n0 = blockIdx.x * 64;
  const int lane = tid & 63, w = tid >> 6;
  const int lr = lane & 15, lg = lane >> 4;
  const int wm = w >> 1, wn = w & 1;  // 4 x 2 waves; per-wave region 32 x 32
  const int srow = tid >> 2, scc = (tid & 3) ^ ((srow >> 1) & 3);
  const unsigned short* Ab = A + (size_t)(m0 + srow) * K + scc * 8;
  const unsigned short* Bb = (tid < 256) ? Bt + (size_t)(n0 + srow) * K + scc * 8 : nullptr;
  f32x4 acc[2][2] = {};
  for (int k0 = 0; k0 < K; k0 += 32) {
    gld16(Ab + k0, (void*)(As + tid * 8));
    if (tid < 256) gld16(Bb + k0, (void*)(Bs + tid * 8));
    __syncthreads();
    bf16x8 af[2], bfr[2];
#pragma unroll
    for (int i = 0; i < 2; ++i) {
      const int row = wm * 32 + i * 16 + lr;
      af[i] = ldsb8(As + row * 32 + ((lg ^ ((row >> 1) & 3)) * 8));
    }
#pragma unroll
    for (int j = 0; j < 2; ++j) {
      const int row = wn * 32 + j * 16 + lr;
      bfr[j] = ldsb8(Bs + row * 32 + ((lg ^ ((row >> 1) & 3)) * 8));
    }
#pragma unroll
    for (int i = 0; i < 2; ++i)
#pragma unroll
      for (int j = 0; j < 2; ++j)
        acc[i][j] = __builtin_amdgcn_mfma_f32_16x16x32_bf16(af[i], bfr[j], acc[i][j], 0, 0, 0);
    __syncthreads();
  }
#pragma unroll
  for (int i = 0; i < 2; ++i)
#pragma unroll
    for (int j = 0; j < 2; ++j) {
      const int row = m0 + wm * 32 + i * 16 + lg * 4;
      const int col = n0 + wn * 32 + j * 16 + lr;
#pragma unroll
      for (int r = 0; r < 4; ++r) C[(size_t)(row + r) * N + col] = acc[i][j][r];
    }
}

// ---------- causal flash attention v9 (unchanged from R9) ----------
__global__ __launch_bounds__(512) void k_attn9(const unsigned short* __restrict__ QKV,
                                               const unsigned short* __restrict__ Vt,
                                               unsigned short* __restrict__ O) {
  __shared__ alignas(16) unsigned short Ks[3][64 * 64];
  __shared__ alignas(16) unsigned short Vs[3][64 * 64];
  const int id = blockIdx.x;
  const int pairIdx = id & 255;
  const int bh = pairIdx >> 3, pi = pairIdx & 7;
  const int j = (id < 256) ? pi : 15 - pi;
  const int b = bh >> 4, h = bh & 15;
  const int q0 = j * 128;
  const int tid = threadIdx.x, lane = tid & 63, w = tid >> 6;
  const int lr = lane & 15, lg = lane >> 4;
  const int lsw = lr & 7;  // XOR key (row&7 / d&7 for all our reads)
  const int qw = q0 + w * 16;
  const unsigned short* Qg = QKV + (size_t)b * TT * SQKV + h * DH;
  const unsigned short* Kg = QKV + (size_t)b * TT * SQKV + DM + h * DH;
  const unsigned short* Vg = Vt + (size_t)bh * 32 * 4096;  // PV-native tiles

  bf16x8 qf[2];
#pragma unroll
  for (int c2 = 0; c2 < 2; ++c2)
    qf[c2] = *(const bf16x8*)(Qg + (size_t)(qw + lr) * SQKV + c2 * 32 + lg * 8);

  f32x4 acco[4] = {};
  float mrun = -1e30f, lrun = 0.f;

  const int krow = tid >> 3, kcc = (tid & 7) ^ (krow & 7);
  const unsigned short* kbase = Kg + (size_t)krow * SQKV + kcc * 8;
  const unsigned short* vbase = Vg + tid * 8;
  auto stage = [&](int buf, int t) {
    gld16(kbase + (size_t)t * 64 * SQKV, (void*)(Ks[buf] + tid * 8));
    gld16(vbase + (size_t)t * 4096, (void*)(Vs[buf] + tid * 8));
  };

  const int nt = 2 * j + 2;
  stage(0, 0);
  stage(1, 1);  // nt >= 2 always
  int buf = 0;
  for (int t = 0; t < nt; ++t) {
    if (t + 1 < nt) {
      asm volatile("s_waitcnt vmcnt(2)" ::: "memory");  // tile t landed; t+1 in flight
    } else {
      asm volatile("s_waitcnt vmcnt(0)" ::: "memory");
    }
    __builtin_amdgcn_s_barrier();
    if (t + 2 < nt) {
      int nb = buf + 2; if (nb >= 3) nb -= 3;
      stage(nb, t + 2);  // targets buf[(t-1)%3]; all waves done with it
    }
    const int s0 = t * 64;
    if (s0 <= qw + 15) {  // not fully masked for this wave
      const unsigned short* Kb_ = Ks[buf];
      const unsigned short* Vb_ = Vs[buf];
      f32x4 st[4] = {};
      __builtin_amdgcn_s_setprio(1);
#pragma unroll
      for (int ct = 0; ct < 4; ++ct)
#pragma unroll
        for (int c2 = 0; c2 < 2; ++c2) {
          bf16x8 kf = ldsb8(Kb_ + (ct * 16 + lr) * 64 + (((c2 * 4 + lg) ^ lsw) * 8));
          st[ct] = __builtin_amdgcn_mfma_f32_16x16x32_bf16(kf, qf[c2], st[ct], 0, 0, 0);
        }
      __builtin_amdgcn_s_setprio(0);
      float p[4][4];
      const bool diag = (s0 + 63 >= qw);
      const int qrel = qw + lr - s0;
      if (diag) {
#pragma unroll
        for (int ct = 0; ct < 4; ++ct)
#pragma unroll
          for (int r = 0; r < 4; ++r) {
            float v = st[ct][r];
            if (ct * 16 + lg * 4 + r > qrel) v = -1e30f;
            p[ct][r] = v;
          }
      } else {
#pragma unroll
        for (int ct = 0; ct < 4; ++ct)
#pragma unroll
          for (int r = 0; r < 4; ++r) p[ct][r] = st[ct][r];
      }
      float m0_ = fmaxf(fmaxf(p[0][0], p[0][1]), p[0][2]);
      float m1_ = fmaxf(fmaxf(p[0][3], p[1][0]), p[1][1]);
      float m2_ = fmaxf(fmaxf(p[1][2], p[1][3]), p[2][0]);
      float m3_ = fmaxf(fmaxf(p[2][1], p[2][2]), p[2][3]);
      float m4_ = fmaxf(fmaxf(p[3][0], p[3][1]), p[3][2]);
      float mx = fmaxf(fmaxf(fmaxf(m0_, m1_), fmaxf(m2_, m3_)), fmaxf(m4_, p[3][3]));
      mx = fmaxf(mx, __shfl_xor(mx, 16));
      mx = fmaxf(mx, __shfl_xor(mx, 32));
      if (!__all(mx <= mrun + 11.5f)) {
        const float mn = fmaxf(mrun, mx);
        const float aa = __builtin_exp2f(mrun - mn);
        mrun = mn;
        lrun *= aa;
        float aab[4];
#pragma unroll
        for (int r = 0; r < 4; ++r) aab[r] = __shfl(aa, lg * 4 + r);
#pragma unroll
        for (int dt = 0; dt < 4; ++dt)
#pragma unroll
          for (int r = 0; r < 4; ++r) acco[dt][r] *= aab[r];
      }
      f32x4 rs4 = {0.f, 0.f, 0.f, 0.f};
#pragma unroll
      for (int ct = 0; ct < 4; ++ct)
#pragma unroll
        for (int r = 0; r < 4; ++r) {
          p[ct][r] = __builtin_exp2f(p[ct][r] - mrun);
          rs4[r] += p[ct][r];
        }
      float rs = (rs4[0] + rs4[1]) + (rs4[2] + rs4[3]);
      rs += __shfl_xor(rs, 16);
      rs += __shfl_xor(rs, 32);
      lrun += rs;
      bf16x8 pf[2];
#pragma unroll
      for (int ks = 0; ks < 2; ++ks) {
        union { unsigned w4[4]; bf16x8 v; } pu;
        pu.w4[0] = cvtpk(p[2 * ks][0], p[2 * ks][1]);
        pu.w4[1] = cvtpk(p[2 * ks][2], p[2 * ks][3]);
        pu.w4[2] = cvtpk(p[2 * ks + 1][0], p[2 * ks + 1][1]);
        pu.w4[3] = cvtpk(p[2 * ks + 1][2], p[2 * ks + 1][3]);
        pf[ks] = pu.v;
      }
      __builtin_amdgcn_s_setprio(1);
#pragma unroll
      for (int dt = 0; dt < 4; ++dt) {
        const unsigned short* Vrow = Vb_ + (dt * 16 + lr) * 64;  // d&7 == lsw
#pragma unroll
        for (int ks = 0; ks < 2; ++ks) {
          bf16x8 vf = ldsb8(Vrow + (((ks * 4 + lg) ^ lsw) * 8));
          acco[dt] = __builtin_amdgcn_mfma_f32_16x16x32_bf16(pf[ks], vf, acco[dt], 0, 0, 0);
        }
      }
      __builtin_amdgcn_s_setprio(0);
    }
    if (++buf >= 3) buf = 0;
  }
  const float linv = 1.f / lrun;
  float lb[4];
#pragma unroll
  for (int r = 0; r < 4; ++r) lb[r] = __shfl(linv, lg * 4 + r);
#pragma unroll
  for (int dt = 0; dt < 4; ++dt)
#pragma unroll
    for (int r = 0; r < 4; ++r) {
      const int q = qw + lg * 4 + r;
      O[(size_t)(b * TT + q) * DM + h * DH + dt * 16 + lr] = f2bf(acco[dt][r] * lb[r]);
    }
}

extern "C" void kernel_launch(void* const* d_in, const int* in_sizes, int n_in,
                              void* d_out, int out_size, void* d_ws, size_t ws_size,
                              hipStream_t stream) {
  const float* x = (const float*)d_in[0];
  const float* wq = (const float*)d_in[1];
  const float* wk = (const float*)d_in[2];
  const float* wv = (const float*)d_in[3];
  const float* wo = (const float*)d_in[4];
  float* out = (float*)d_out;
  char* ws = (char*)d_ws;
  const size_t MB = 1u << 20;
  // ws layout (48 MB):
  unsigned short* xb = (unsigned short*)(ws);             // 8MB: x bf16; reused as attn-out
  unsigned short* wqt = (unsigned short*)(ws + 8 * MB);   // 2MB x4 contiguous: wq^T wk^T wv^T wo^T
  unsigned short* wot = (unsigned short*)(ws + 14 * MB);
  unsigned short* QKVb = (unsigned short*)(ws + 16 * MB); // 24MB: [MR][3072] (V region unused)
  unsigned short* Vtb = (unsigned short*)(ws + 40 * MB);  // 8MB: PV-native [B*H][32][4096]

  k_prep<<<dim3(6144), 256, 0, stream>>>(x, wq, wk, wv, wo, xb, wqt);
  // Q columns (col < DM) pre-scaled by 0.125*log2(e); V columns -> PV-native Vtb
  k_gemm_qkv<<<dim3(24, 32), 512, 0, stream>>>(xb, wqt, QKVb, 0.18033688f, Vtb);
  k_attn9<<<dim3(512), 512, 0, stream>>>(QKVb, Vtb, xb);
  k_gemm_out<<<dim3(16, 32), 512, 0, stream>>>(xb, wot, out);
}